// Round 1
// baseline (186.175 us; speedup 1.0000x reference)
//
#include <hip/hip_runtime.h>
#include <hip/hip_bf16.h>
#include <stdint.h>

#define B_ 2
#define S_ 2048
#define H_ 32
#define D_ 128
#define R_ (B_*H_*S_)   // 131072 rows per tensor (head-major layout)

typedef __bf16 bf16x8 __attribute__((ext_vector_type(8)));
typedef float  f32x4  __attribute__((ext_vector_type(4)));

__device__ __forceinline__ unsigned short f2bf(float f) {
  unsigned u = __float_as_uint(f);
  u += 0x7FFFu + ((u >> 16) & 1u);
  return (unsigned short)(u >> 16);
}

// Prep 1: q,k [B,S,H,D] fp32 -> [B,H,S,D] bf16 (head-major, contiguous tiles).
// 8 rows per 256-thread block; 32 threads per row, float4 each.
__global__ __launch_bounds__(256) void prep_qk(
    const float* __restrict__ q, const float* __restrict__ k,
    unsigned short* __restrict__ qb, unsigned short* __restrict__ kb,
    float* __restrict__ out0) {
  if (blockIdx.x == 0 && threadIdx.x == 0) out0[0] = 0.f;  // zero the scalar output
  const int t = threadIdx.x;
  const int rowblk = blockIdx.x * 8 + (t >> 5);
  const float* src; unsigned short* dst; int r;
  if (rowblk < R_) { src = q; dst = qb; r = rowblk; }
  else             { src = k; dst = kb; r = rowblk - R_; }
  const int b  = r / (H_ * S_);
  const int hs = r % (H_ * S_);
  const int h  = hs / S_;
  const int s  = hs % S_;
  const size_t inoff = (((size_t)b * S_ + s) * H_ + h) * D_;
  const int lane32 = t & 31;
  const float4 v4 = *reinterpret_cast<const float4*>(src + inoff + lane32 * 4);
  ushort4 o;
  o.x = f2bf(v4.x); o.y = f2bf(v4.y); o.z = f2bf(v4.z); o.w = f2bf(v4.w);
  *reinterpret_cast<ushort4*>(dst + (size_t)r * D_ + lane32 * 4) = o;
}

// Prep 2: vsum[b,h,s] = sum_d v[b,s,h,d]   (fp32). One wave per row.
__global__ __launch_bounds__(256) void prep_vsum(
    const float* __restrict__ v, float* __restrict__ vsum) {
  const int t = threadIdx.x;
  const int r = blockIdx.x * 4 + (t >> 6);
  const int lane = t & 63;
  const int b  = r / (H_ * S_);
  const int hs = r % (H_ * S_);
  const int h  = hs / S_;
  const int s  = hs % S_;
  const size_t inoff = (((size_t)b * S_ + s) * H_ + h) * D_;
  const float2 x = *reinterpret_cast<const float2*>(v + inoff + lane * 2);
  float sum = x.x + x.y;
  #pragma unroll
  for (int m = 1; m < 64; m <<= 1) sum += __shfl_xor(sum, m);
  if (lane == 0) vsum[r] = sum;
}

// Main: per block = one (b,h) and a 64-row q-tile (4 waves x 16 rows).
// K staged to LDS in 32-row tiles (XOR-swizzled to kill bank conflicts).
// Scores via mfma_f32_16x16x32_bf16; softmax-weighted vsum accumulation.
__global__ __launch_bounds__(256) void attn_sum(
    const unsigned short* __restrict__ qb, const unsigned short* __restrict__ kb,
    const float* __restrict__ vsum, float* __restrict__ out) {
  __shared__ uint4 kt_lds[32 * 16];   // 8 KB, 16B-chunk XOR swizzle
  __shared__ float vs_lds[32];

  const int bh = blockIdx.y;                       // 0..63
  const int qt = (gridDim.x - 1) - blockIdx.x;     // reversed: heavy tiles first
  const int t  = threadIdx.x;
  const int w  = t >> 6;
  const int l  = t & 63;
  const int l16 = l & 15, lg = l >> 4;

  const int qrow0 = qt * 64 + w * 16;
  const size_t base = (size_t)bh * S_ * D_;

  // Q fragments for this wave's 16 rows, all of D, hoisted to registers.
  bf16x8 qfrag[4];
  {
    const unsigned short* qp = qb + base + (size_t)(qrow0 + l16) * D_ + lg * 8;
    #pragma unroll
    for (int dblk = 0; dblk < 4; ++dblk)
      qfrag[dblk] = *reinterpret_cast<const bf16x8*>(qp + dblk * 32);
  }

  float num[4] = {0.f,0.f,0.f,0.f}, den[4] = {0.f,0.f,0.f,0.f};
  const float scale = 0.088388347648318447f;  // 1/sqrt(128)

  const int ktmax = qt * 2 + 1;                // covers k up to qt*64+63
  for (int kt = 0; kt <= ktmax; ++kt) {
    __syncthreads();
    {
      // stage 32x128 bf16 = 8 KB contiguous; 2 x 16B chunks per thread
      const uint4* g = reinterpret_cast<const uint4*>(kb + base + (size_t)kt * 32 * D_);
      #pragma unroll
      for (int j = 0; j < 2; ++j) {
        const int ci  = t * 2 + j;
        const int row = ci >> 4, c16 = ci & 15;
        kt_lds[row * 16 + (c16 ^ (row & 7))] = g[ci];
      }
      if (t < 32) vs_lds[t] = vsum[(size_t)bh * S_ + kt * 32 + t];
    }
    __syncthreads();

    if (kt * 32 > qrow0 + 15) continue;  // wave fully masked (barrier counts stay uniform)

    #pragma unroll
    for (int c = 0; c < 2; ++c) {
      f32x4 sacc = {0.f, 0.f, 0.f, 0.f};
      const int row = c * 16 + l16;
      #pragma unroll
      for (int dblk = 0; dblk < 4; ++dblk) {
        const bf16x8 bfrag = *reinterpret_cast<const bf16x8*>(
            &kt_lds[row * 16 + ((dblk * 4 + lg) ^ (row & 7))]);
        sacc = __builtin_amdgcn_mfma_f32_16x16x32_bf16(qfrag[dblk], bfrag, sacc, 0, 0, 0);
      }
      const int kg  = kt * 32 + c * 16 + l16;
      const float vsv = vs_lds[c * 16 + l16];
      #pragma unroll
      for (int reg = 0; reg < 4; ++reg) {
        const int qg = qrow0 + lg * 4 + reg;   // C/D: row=(lane>>4)*4+reg, col=lane&15
        if (kg <= qg) {
          const float e = __expf(sacc[reg] * scale);
          den[reg] += e;
          num[reg] += e * vsv;
        }
      }
    }
  }

  // reduce across the 16 lanes sharing lg (cols) -> full row sums
  #pragma unroll
  for (int m = 1; m < 16; m <<= 1) {
    #pragma unroll
    for (int reg = 0; reg < 4; ++reg) {
      num[reg] += __shfl_xor(num[reg], m);
      den[reg] += __shfl_xor(den[reg], m);
    }
  }
  float contrib = 0.f;
  #pragma unroll
  for (int reg = 0; reg < 4; ++reg) contrib += num[reg] / den[reg];
  // sum across the 4 lane-groups (each group's value replicated 16x)
  contrib += __shfl_xor(contrib, 16);
  contrib += __shfl_xor(contrib, 32);
  if (l == 0) atomicAdd(out, contrib);
}

extern "C" void kernel_launch(void* const* d_in, const int* in_sizes, int n_in,
                              void* d_out, int out_size, void* d_ws, size_t ws_size,
                              hipStream_t stream) {
  const float* q = (const float*)d_in[0];
  const float* k = (const float*)d_in[1];
  const float* v = (const float*)d_in[2];
  float* out = (float*)d_out;

  unsigned short* qb = (unsigned short*)d_ws;                 // 32 MiB
  unsigned short* kb = qb + (size_t)R_ * D_;                  // 32 MiB
  float* vsum = (float*)(kb + (size_t)R_ * D_);               // 512 KiB

  hipLaunchKernelGGL(prep_qk,  dim3(2 * R_ / 8), dim3(256), 0, stream, q, k, qb, kb, out);
  hipLaunchKernelGGL(prep_vsum, dim3(R_ / 4),    dim3(256), 0, stream, v, vsum);
  hipLaunchKernelGGL(attn_sum, dim3(S_ / 64, B_ * H_), dim3(256), 0, stream,
                     qb, kb, vsum, out);
}

// Round 2
// 140.947 us; speedup vs baseline: 1.3209x; 1.3209x over previous
//
#include <hip/hip_runtime.h>
#include <hip/hip_bf16.h>
#include <stdint.h>

#define B_ 2
#define S_ 2048
#define H_ 32
#define D_ 128
#define R_ (B_*H_*S_)   // 131072 rows per tensor (head-major layout)

typedef __bf16 bf16x8 __attribute__((ext_vector_type(8)));
typedef float  f32x16 __attribute__((ext_vector_type(16)));

#if __has_builtin(__builtin_amdgcn_exp2f)
#define EXP2F(x) __builtin_amdgcn_exp2f(x)
#else
#define EXP2F(x) exp2f(x)
#endif

__device__ __forceinline__ unsigned short f2bf(float f) {
  unsigned u = __float_as_uint(f);
  u += 0x7FFFu + ((u >> 16) & 1u);
  return (unsigned short)(u >> 16);
}

// Prep 1: q,k [B,S,H,D] fp32 -> [B,H,S,D] bf16. Q gets scale*log2(e) folded in
// so the main kernel's softmax is a bare exp2.
__global__ __launch_bounds__(256) void prep_qk(
    const float* __restrict__ q, const float* __restrict__ k,
    unsigned short* __restrict__ qb, unsigned short* __restrict__ kb,
    float* __restrict__ out0) {
  if (blockIdx.x == 0 && threadIdx.x == 0) out0[0] = 0.f;
  const int t = threadIdx.x;
  const int rowblk = blockIdx.x * 8 + (t >> 5);
  const float* src; unsigned short* dst; int r; float sc;
  if (rowblk < R_) { src = q; dst = qb; r = rowblk; sc = 0.0883883476483184f * 1.4426950408889634f; }
  else             { src = k; dst = kb; r = rowblk - R_; sc = 1.0f; }
  const int b  = r / (H_ * S_);
  const int hs = r % (H_ * S_);
  const int h  = hs / S_;
  const int s  = hs % S_;
  const size_t inoff = (((size_t)b * S_ + s) * H_ + h) * D_;
  const int lane32 = t & 31;
  const float4 v4 = *reinterpret_cast<const float4*>(src + inoff + lane32 * 4);
  ushort4 o;
  o.x = f2bf(v4.x * sc); o.y = f2bf(v4.y * sc); o.z = f2bf(v4.z * sc); o.w = f2bf(v4.w * sc);
  *reinterpret_cast<ushort4*>(dst + (size_t)r * D_ + lane32 * 4) = o;
}

// Prep 2: vsum[b,h,s] = sum_d v[b,s,h,d]   (fp32). One wave per row.
__global__ __launch_bounds__(256) void prep_vsum(
    const float* __restrict__ v, float* __restrict__ vsum) {
  const int t = threadIdx.x;
  const int r = blockIdx.x * 4 + (t >> 6);
  const int lane = t & 63;
  const int b  = r / (H_ * S_);
  const int hs = r % (H_ * S_);
  const int h  = hs / S_;
  const int s  = hs % S_;
  const size_t inoff = (((size_t)b * S_ + s) * H_ + h) * D_;
  const float2 x = *reinterpret_cast<const float2*>(v + inoff + lane * 2);
  float sum = x.x + x.y;
  #pragma unroll
  for (int m = 1; m < 64; m <<= 1) sum += __shfl_xor(sum, m);
  if (lane == 0) vsum[r] = sum;
}

// Main: block = one (b,h) x 128 q-rows (4 waves x 32 rows). K staged in
// 64-row double-buffered LDS tiles via global_load_lds with pre-swizzled
// global source (linear LDS dest); reads apply the same XOR -> conflict-free.
// Scores via mfma_f32_32x32x16_bf16 (2x less LDS B-traffic per FLOP).
__global__ __launch_bounds__(256, 4) void attn_sum(
    const unsigned short* __restrict__ qg_, const unsigned short* __restrict__ kg_,
    const float* __restrict__ vsum, float* __restrict__ out) {
  __shared__ uint4 kbuf[2][64 * 16];   // 2 x 16KB

  const int bh = blockIdx.y;                       // 0..63
  const int qt = (int)(gridDim.x - 1) - (int)blockIdx.x;  // heavy tiles first
  const int t  = threadIdx.x;
  const int w  = t >> 6;
  const int l  = t & 63;
  const int ln = l & 31, l5 = l >> 5;

  const size_t base = (size_t)bh * S_ * D_;
  const int qrow0 = qt * 128 + w * 32;

  // A-frags: 32 q-rows (m = lane&31), d-chunk = kb8*16 + (lane>>5)*8, hoisted.
  bf16x8 qfrag[8];
  {
    const unsigned short* qp = qg_ + base + (size_t)(qrow0 + ln) * D_ + l5 * 8;
    #pragma unroll
    for (int kb8 = 0; kb8 < 8; ++kb8)
      qfrag[kb8] = *reinterpret_cast<const bf16x8*>(qp + kb8 * 16);
  }

  float num[16], den[16];
  #pragma unroll
  for (int r = 0; r < 16; ++r) { num[r] = 0.f; den[r] = 0.f; }

  const int nkt = 2 * qt + 2;              // 64-row k-tiles
  const unsigned short* ksrc0 = kg_ + base;

  // Prologue: stage tile 0 into buf 0.
  #pragma unroll
  for (int i = 0; i < 4; ++i) {
    const int idx = w * 256 + i * 64 + l;  // 16B-chunk index in tile
    const int row = idx >> 4, ch = idx & 15;
    const unsigned short* src = ksrc0 + row * D_ + ((ch ^ (row & 7)) * 8);
    __builtin_amdgcn_global_load_lds(
        (const __attribute__((address_space(1))) void*)src,
        (__attribute__((address_space(3))) void*)(&kbuf[0][idx & ~63]), 16, 0, 0);
  }
  asm volatile("s_waitcnt vmcnt(0)" ::: "memory");
  __syncthreads();

  for (int kt = 0; kt < nkt; ++kt) {
    const int cur = kt & 1;
    if (kt + 1 < nkt) {  // prefetch next tile into the other buffer
      const unsigned short* ksrc = ksrc0 + (size_t)(kt + 1) * 64 * D_;
      #pragma unroll
      for (int i = 0; i < 4; ++i) {
        const int idx = w * 256 + i * 64 + l;
        const int row = idx >> 4, ch = idx & 15;
        const unsigned short* src = ksrc + row * D_ + ((ch ^ (row & 7)) * 8);
        __builtin_amdgcn_global_load_lds(
            (const __attribute__((address_space(1))) void*)src,
            (__attribute__((address_space(3))) void*)(&kbuf[cur ^ 1][idx & ~63]), 16, 0, 0);
      }
    }
    const int ktb = kt * 64;
    if (ktb <= qrow0 + 31) {               // wave-uniform causal skip
      #pragma unroll
      for (int nb = 0; nb < 2; ++nb) {
        const int kbase = ktb + nb * 32;
        if (kbase > qrow0 + 31) continue;
        const int row = nb * 32 + ln;      // B: n = lane&31 (k-row)
        const int rsw = row & 7;
        const uint4* tb = &kbuf[cur][row * 16];
        f32x16 sacc = {0.f,0.f,0.f,0.f,0.f,0.f,0.f,0.f,
                       0.f,0.f,0.f,0.f,0.f,0.f,0.f,0.f};
        #pragma unroll
        for (int kb8 = 0; kb8 < 8; ++kb8) {
          const bf16x8 bf = *reinterpret_cast<const bf16x8*>(&tb[(kb8 * 2 + l5) ^ rsw]);
          sacc = __builtin_amdgcn_mfma_f32_32x32x16_bf16(qfrag[kb8], bf, sacc, 0, 0, 0);
        }
        const float vsv = vsum[(size_t)bh * S_ + kbase + ln];
        if (kbase + 31 <= qrow0) {
          // interior tile: no mask -> 3 ops/element
          #pragma unroll
          for (int r = 0; r < 16; ++r) {
            const float e = EXP2F(sacc[r]);
            den[r] += e;
            num[r] = fmaf(e, vsv, num[r]);
          }
        } else {
          // diagonal tile: per-element causal mask
          const int kgc = kbase + ln;
          #pragma unroll
          for (int r = 0; r < 16; ++r) {
            const int qgr = qrow0 + (r & 3) + 8 * (r >> 2) + 4 * l5;
            const float e = (kgc <= qgr) ? EXP2F(sacc[r]) : 0.f;
            den[r] += e;
            num[r] = fmaf(e, vsv, num[r]);
          }
        }
      }
    }
    asm volatile("s_waitcnt vmcnt(0)" ::: "memory");
    __syncthreads();
  }

  // Reduce across the 32 lanes sharing l5 (columns) -> full row sums.
  #pragma unroll
  for (int m = 1; m < 32; m <<= 1) {
    #pragma unroll
    for (int r = 0; r < 16; ++r) {
      num[r] += __shfl_xor(num[r], m);
      den[r] += __shfl_xor(den[r], m);
    }
  }
  float contrib = 0.f;
  #pragma unroll
  for (int r = 0; r < 16; ++r) contrib += num[r] / den[r];
  contrib += __shfl_xor(contrib, 32);   // other l5 half covers rows +4
  if (l == 0) atomicAdd(out, contrib);
}

extern "C" void kernel_launch(void* const* d_in, const int* in_sizes, int n_in,
                              void* d_out, int out_size, void* d_ws, size_t ws_size,
                              hipStream_t stream) {
  const float* q = (const float*)d_in[0];
  const float* k = (const float*)d_in[1];
  const float* v = (const float*)d_in[2];
  float* out = (float*)d_out;

  unsigned short* qb = (unsigned short*)d_ws;                 // 32 MiB
  unsigned short* kb = qb + (size_t)R_ * D_;                  // 32 MiB
  float* vsum = (float*)(kb + (size_t)R_ * D_);               // 512 KiB

  hipLaunchKernelGGL(prep_qk,  dim3(2 * R_ / 8), dim3(256), 0, stream, q, k, qb, kb, out);
  hipLaunchKernelGGL(prep_vsum, dim3(R_ / 4),    dim3(256), 0, stream, v, vsum);
  hipLaunchKernelGGL(attn_sum, dim3(S_ / 128, B_ * H_), dim3(256), 0, stream,
                     qb, kb, vsum, out);
}

// Round 3
// 132.761 us; speedup vs baseline: 1.4023x; 1.0617x over previous
//
#include <hip/hip_runtime.h>
#include <hip/hip_bf16.h>
#include <stdint.h>

#define B_ 2
#define S_ 2048
#define H_ 32
#define D_ 128
#define R_ (B_*H_*S_)   // 131072 rows per tensor (head-major layout)

typedef __bf16 bf16x8 __attribute__((ext_vector_type(8)));
typedef float  f32x16 __attribute__((ext_vector_type(16)));

#if __has_builtin(__builtin_amdgcn_exp2f)
#define EXP2F(x) __builtin_amdgcn_exp2f(x)
#else
#define EXP2F(x) exp2f(x)
#endif

#define AS1 __attribute__((address_space(1)))
#define AS3 __attribute__((address_space(3)))

__device__ __forceinline__ unsigned short f2bf(float f) {
  unsigned u = __float_as_uint(f);
  u += 0x7FFFu + ((u >> 16) & 1u);
  return (unsigned short)(u >> 16);
}

// Prep 1: q,k [B,S,H,D] fp32 -> [B,H,S,D] bf16. Q gets scale*log2(e) folded in
// so the main kernel's softmax is a bare exp2.
__global__ __launch_bounds__(256) void prep_qk(
    const float* __restrict__ q, const float* __restrict__ k,
    unsigned short* __restrict__ qb, unsigned short* __restrict__ kb,
    float* __restrict__ out0) {
  if (blockIdx.x == 0 && threadIdx.x == 0) out0[0] = 0.f;
  const int t = threadIdx.x;
  const int rowblk = blockIdx.x * 8 + (t >> 5);
  const float* src; unsigned short* dst; int r; float sc;
  if (rowblk < R_) { src = q; dst = qb; r = rowblk; sc = 0.0883883476483184f * 1.4426950408889634f; }
  else             { src = k; dst = kb; r = rowblk - R_; sc = 1.0f; }
  const int b  = r / (H_ * S_);
  const int hs = r % (H_ * S_);
  const int h  = hs / S_;
  const int s  = hs % S_;
  const size_t inoff = (((size_t)b * S_ + s) * H_ + h) * D_;
  const int lane32 = t & 31;
  const float4 v4 = *reinterpret_cast<const float4*>(src + inoff + lane32 * 4);
  ushort4 o;
  o.x = f2bf(v4.x * sc); o.y = f2bf(v4.y * sc); o.z = f2bf(v4.z * sc); o.w = f2bf(v4.w * sc);
  *reinterpret_cast<ushort4*>(dst + (size_t)r * D_ + lane32 * 4) = o;
}

// Prep 2: vsum[b,h,s] = sum_d v[b,s,h,d]   (fp32). One wave per row.
__global__ __launch_bounds__(256) void prep_vsum(
    const float* __restrict__ v, float* __restrict__ vsum) {
  const int t = threadIdx.x;
  const int r = blockIdx.x * 4 + (t >> 6);
  const int lane = t & 63;
  const int b  = r / (H_ * S_);
  const int hs = r % (H_ * S_);
  const int h  = hs / S_;
  const int s  = hs % S_;
  const size_t inoff = (((size_t)b * S_ + s) * H_ + h) * D_;
  const float2 x = *reinterpret_cast<const float2*>(v + inoff + lane * 2);
  float sum = x.x + x.y;
  #pragma unroll
  for (int m = 1; m < 64; m <<= 1) sum += __shfl_xor(sum, m);
  if (lane == 0) vsum[r] = sum;
}

// Main: block = one (b,h) x 128 q-rows (4 waves x 32 rows).
// 3-buffer LDS pipeline, prefetch depth 2, counted vmcnt(5) (never drain to 0
// in steady state). K staged via global_load_lds with pre-swizzled global
// source (linear LDS dest, same XOR on read -> conflict-free ds_read_b128).
// vsum rides the same DMA batch so the vm counter stays exact (5 ops/tile).
// Balanced grid: every 256-consecutive-block window contains all qt values.
__global__ __launch_bounds__(256, 3) void attn_sum(
    const unsigned short* __restrict__ qg_, const unsigned short* __restrict__ kg_,
    const float* __restrict__ vsum, float* __restrict__ out) {
  __shared__ uint4 kbuf[3][64 * 16];   // 3 x 16KB
  __shared__ float vsbuf[3][64];       // 3 x 256B

  // Balanced mapping: slot s in [0,256) x round r in [0,4)
  const int id = blockIdx.x;
  const int s_ = id & 255;
  const int r_ = id >> 8;
  const int m_ = s_ & 15;
  const int qt = (r_ & 1) ? m_ : 15 - m_;
  const int bh = r_ * 16 + (s_ >> 4);

  const int t  = threadIdx.x;
  const int w  = t >> 6;
  const int l  = t & 63;
  const int ln = l & 31, l5 = l >> 5;

  const size_t base = (size_t)bh * S_ * D_;
  const int qrow0 = qt * 128 + w * 32;
  const int nkt = 2 * qt + 2;              // 64-row k-tiles
  const unsigned short* ksrc0 = kg_ + base;
  const float* vsrc0 = vsum + (size_t)bh * S_;

  // A-frags: 32 q-rows (m = lane&31), d-chunk = kb8*16 + (lane>>5)*8, hoisted.
  bf16x8 qfrag[8];
  {
    const unsigned short* qp = qg_ + base + (size_t)(qrow0 + ln) * D_ + l5 * 8;
    #pragma unroll
    for (int kb8 = 0; kb8 < 8; ++kb8)
      qfrag[kb8] = *reinterpret_cast<const bf16x8*>(qp + kb8 * 16);
  }

  // Stage one 64-row K-tile (+vsum strip) into LDS slot: 5 DMA ops per wave.
  auto stage = [&](int j, int slot) {
    const unsigned short* ksrc = ksrc0 + (size_t)j * 64 * D_;
    #pragma unroll
    for (int i = 0; i < 4; ++i) {
      const int idx = w * 256 + i * 64 + l;  // 16B-chunk index in tile
      const int row = idx >> 4, ch = idx & 15;
      const unsigned short* src = ksrc + row * D_ + ((ch ^ (row & 7)) * 8);
      __builtin_amdgcn_global_load_lds(
          (const AS1 void*)src, (AS3 void*)(&kbuf[slot][idx & ~63]), 16, 0, 0);
    }
    __builtin_amdgcn_global_load_lds(
        (const AS1 void*)(vsrc0 + j * 64 + l), (AS3 void*)(&vsbuf[slot][0]), 4, 0, 0);
  };

  float num[16], den[16];
  #pragma unroll
  for (int r = 0; r < 16; ++r) { num[r] = 0.f; den[r] = 0.f; }

  // Prologue: depth-2 prefetch.
  stage(0, 0);
  stage(1, 1);

  int cur = 0;
  for (int kt = 0; kt < nkt; ++kt) {
    // Wait for tile kt's batch (5 newer ops = tile kt+1's batch in flight).
    if (kt <= nkt - 2) asm volatile("s_waitcnt vmcnt(5)" ::: "memory");
    else               asm volatile("s_waitcnt vmcnt(0)" ::: "memory");
    __syncthreads();

    const int ktb = kt * 64;
    if (ktb <= qrow0 + 31) {               // wave-uniform causal skip
      #pragma unroll
      for (int nb = 0; nb < 2; ++nb) {
        const int kbase = ktb + nb * 32;
        if (kbase > qrow0 + 31) continue;
        const int row = nb * 32 + ln;      // B: n = lane&31 (k-row)
        const int rsw = row & 7;
        const uint4* tb = &kbuf[cur][row * 16];
        f32x16 sacc = {0.f,0.f,0.f,0.f,0.f,0.f,0.f,0.f,
                       0.f,0.f,0.f,0.f,0.f,0.f,0.f,0.f};
        __builtin_amdgcn_s_setprio(1);
        #pragma unroll
        for (int kb8 = 0; kb8 < 8; ++kb8) {
          const bf16x8 bf = *reinterpret_cast<const bf16x8*>(&tb[(kb8 * 2 + l5) ^ rsw]);
          sacc = __builtin_amdgcn_mfma_f32_32x32x16_bf16(qfrag[kb8], bf, sacc, 0, 0, 0);
        }
        __builtin_amdgcn_s_setprio(0);
        const float vsv = vsbuf[cur][nb * 32 + ln];
        if (kbase + 31 <= qrow0) {
          // interior tile: no mask -> 3 ops/element
          #pragma unroll
          for (int r = 0; r < 16; ++r) {
            const float e = EXP2F(sacc[r]);
            den[r] += e;
            num[r] = fmaf(e, vsv, num[r]);
          }
        } else {
          // diagonal tile: per-element causal mask
          const int kgc = kbase + ln;
          #pragma unroll
          for (int r = 0; r < 16; ++r) {
            const int qgr = qrow0 + (r & 3) + 8 * (r >> 2) + 4 * l5;
            const float e = (kgc <= qgr) ? EXP2F(sacc[r]) : 0.f;
            den[r] += e;
            num[r] = fmaf(e, vsv, num[r]);
          }
        }
      }
    }

    // Prefetch tile kt+2 into the buffer freed by tile kt-1 (race-free: all
    // waves passed the barrier above, so all reads of that buffer are done).
    if (kt + 2 < nkt) stage(kt + 2, (cur + 2 >= 3) ? cur - 1 : cur + 2);
    cur = (cur == 2) ? 0 : cur + 1;
  }

  // Reduce across the 32 lanes sharing l5 (columns) -> full row sums.
  #pragma unroll
  for (int m = 1; m < 32; m <<= 1) {
    #pragma unroll
    for (int r = 0; r < 16; ++r) {
      num[r] += __shfl_xor(num[r], m);
      den[r] += __shfl_xor(den[r], m);
    }
  }
  float contrib = 0.f;
  #pragma unroll
  for (int r = 0; r < 16; ++r) contrib += num[r] / den[r];
  contrib += __shfl_xor(contrib, 32);   // other l5 half covers rows +4
  if (l == 0) atomicAdd(out, contrib);
}

extern "C" void kernel_launch(void* const* d_in, const int* in_sizes, int n_in,
                              void* d_out, int out_size, void* d_ws, size_t ws_size,
                              hipStream_t stream) {
  const float* q = (const float*)d_in[0];
  const float* k = (const float*)d_in[1];
  const float* v = (const float*)d_in[2];
  float* out = (float*)d_out;

  unsigned short* qb = (unsigned short*)d_ws;                 // 32 MiB
  unsigned short* kb = qb + (size_t)R_ * D_;                  // 32 MiB
  float* vsum = (float*)(kb + (size_t)R_ * D_);               // 512 KiB

  hipLaunchKernelGGL(prep_qk,  dim3(2 * R_ / 8), dim3(256), 0, stream, q, k, qb, kb, out);
  hipLaunchKernelGGL(prep_vsum, dim3(R_ / 4),    dim3(256), 0, stream, v, vsum);
  hipLaunchKernelGGL(attn_sum, dim3((S_ / 128) * B_ * H_), dim3(256), 0, stream,
                     qb, kb, vsum, out);
}

// Round 4
// 129.140 us; speedup vs baseline: 1.4417x; 1.0280x over previous
//
#include <hip/hip_runtime.h>
#include <hip/hip_bf16.h>
#include <stdint.h>

#define B_ 2
#define S_ 2048
#define H_ 32
#define D_ 128
#define R_ (B_*H_*S_)   // 131072 rows per tensor (head-major layout)
#define QKBLKS (2 * R_ / 8)

typedef __bf16 bf16x8 __attribute__((ext_vector_type(8)));
typedef float  f32x16 __attribute__((ext_vector_type(16)));

#if __has_builtin(__builtin_amdgcn_exp2f)
#define EXP2F(x) __builtin_amdgcn_exp2f(x)
#else
#define EXP2F(x) exp2f(x)
#endif

#define AS1 __attribute__((address_space(1)))
#define AS3 __attribute__((address_space(3)))

__device__ __forceinline__ unsigned short f2bf(float f) {
  unsigned u = __float_as_uint(f);
  u += 0x7FFFu + ((u >> 16) & 1u);
  return (unsigned short)(u >> 16);
}

// Fused prep: blocks [0, QKBLKS): q,k [B,S,H,D] fp32 -> [B,H,S,D] bf16
// (Q gets scale*log2e folded in); blocks [QKBLKS, ...): vsum[b,h,s] = sum_d v.
__global__ __launch_bounds__(256) void prep(
    const float* __restrict__ q, const float* __restrict__ k,
    const float* __restrict__ v,
    unsigned short* __restrict__ qb, unsigned short* __restrict__ kb,
    float* __restrict__ vsum, float* __restrict__ out0) {
  const int bid = blockIdx.x;
  const int t = threadIdx.x;
  if (bid == 0 && t == 0) out0[0] = 0.f;
  if (bid < QKBLKS) {
    const int rowblk = bid * 8 + (t >> 5);
    const float* src; unsigned short* dst; int r; float sc;
    if (rowblk < R_) { src = q; dst = qb; r = rowblk; sc = 0.0883883476483184f * 1.4426950408889634f; }
    else             { src = k; dst = kb; r = rowblk - R_; sc = 1.0f; }
    const int b  = r / (H_ * S_);
    const int hs = r % (H_ * S_);
    const int h  = hs / S_;
    const int s  = hs % S_;
    const size_t inoff = (((size_t)b * S_ + s) * H_ + h) * D_;
    const int lane32 = t & 31;
    const float4 v4 = *reinterpret_cast<const float4*>(src + inoff + lane32 * 4);
    ushort4 o;
    o.x = f2bf(v4.x * sc); o.y = f2bf(v4.y * sc); o.z = f2bf(v4.z * sc); o.w = f2bf(v4.w * sc);
    *reinterpret_cast<ushort4*>(dst + (size_t)r * D_ + lane32 * 4) = o;
  } else {
    const int r = (bid - QKBLKS) * 4 + (t >> 6);
    const int lane = t & 63;
    const int b  = r / (H_ * S_);
    const int hs = r % (H_ * S_);
    const int h  = hs / S_;
    const int s  = hs % S_;
    const size_t inoff = (((size_t)b * S_ + s) * H_ + h) * D_;
    const float2 x = *reinterpret_cast<const float2*>(v + inoff + lane * 2);
    float sum = x.x + x.y;
    #pragma unroll
    for (int m = 1; m < 64; m <<= 1) sum += __shfl_xor(sum, m);
    if (lane == 0) vsum[r] = sum;
  }
}

// Main: block = one (b,h) x 128 q-rows (4 waves x 32 rows).
// K staged into LDS in FRAGMENT-MAJOR order (flat idx ((nb*8+kb8)*2+l5)*32+ln)
// via global_load_lds with per-lane pre-permuted global source and linear LDS
// dest. Every ds_read_b128 is then 64 lanes x contiguous 16B = bank-optimal,
// and all 16 fragment reads share ONE address register + immediate offsets.
// 2-buffer depth-1 pipeline: {vmcnt(0); barrier; stage(kt+1); compute(kt)} --
// the drain covers DMAs issued a full compute phase earlier. 33KB LDS -> 4
// blocks/CU (16 waves).
__global__ __launch_bounds__(256, 4) void attn_sum(
    const unsigned short* __restrict__ qg_, const unsigned short* __restrict__ kg_,
    const float* __restrict__ vsum, float* __restrict__ out) {
  __shared__ uint4 kbuf[2][1024];      // 2 x 16KB
  __shared__ float vsbuf[2][64];       // 2 x 256B

  // Balanced mapping: every 256-consecutive-id window holds all qt values.
  const int id = blockIdx.x;
  const int s_ = id & 255;
  const int r_ = id >> 8;
  const int m_ = s_ & 15;
  const int qt = (r_ & 1) ? m_ : 15 - m_;
  const int bh = r_ * 16 + (s_ >> 4);

  const int t  = threadIdx.x;
  const int w  = t >> 6;
  const int l  = t & 63;
  const int ln = l & 31, l5 = l >> 5;

  const size_t base = (size_t)bh * S_ * D_;
  const int qrow0 = qt * 128 + w * 32;
  const int nkt = 2 * qt + 2;              // 64-row k-tiles
  const unsigned short* ksrc0 = kg_ + base;
  const float* vsrc0 = vsum + (size_t)bh * S_;

  // A-frags: 32 q-rows (m = lane&31), k-chunk d = kb8*16 + l5*8 .. +8.
  bf16x8 qfrag[8];
  {
    const unsigned short* qp = qg_ + base + (size_t)(qrow0 + ln) * D_ + l5 * 8;
    #pragma unroll
    for (int kb8 = 0; kb8 < 8; ++kb8)
      qfrag[kb8] = *reinterpret_cast<const bf16x8*>(qp + kb8 * 16);
  }

  // Stage one 64-row K-tile (+vsum strip): 5 DMA ops per wave, fragment-major.
  auto stage = [&](int j, int slot) {
    const unsigned short* ksrc = ksrc0 + (size_t)j * 64 * D_;
    #pragma unroll
    for (int i = 0; i < 4; ++i) {
      const int f   = w * 256 + i * 64 + l;      // flat fragment-major chunk id
      const int ln_ = f & 31, l5_ = (f >> 5) & 1;
      const int kb8_ = (f >> 6) & 7, nb_ = (f >> 9) & 1;
      const unsigned short* src = ksrc + (nb_ * 32 + ln_) * D_ + (kb8_ * 2 + l5_) * 8;
      __builtin_amdgcn_global_load_lds(
          (const AS1 void*)src, (AS3 void*)(&kbuf[slot][f & ~63]), 16, 0, 0);
    }
    __builtin_amdgcn_global_load_lds(
        (const AS1 void*)(vsrc0 + j * 64 + l), (AS3 void*)(&vsbuf[slot][0]), 4, 0, 0);
  };

  float num[16], den[16];
  #pragma unroll
  for (int r = 0; r < 16; ++r) { num[r] = 0.f; den[r] = 0.f; }

  stage(0, 0);
  int cur = 0;
  for (int kt = 0; kt < nkt; ++kt) {
    asm volatile("s_waitcnt vmcnt(0)" ::: "memory");
    __syncthreads();
    if (kt + 1 < nkt) stage(kt + 1, cur ^ 1);

    const int ktb = kt * 64;
    if (ktb <= qrow0 + 31) {               // wave-uniform causal skip
      const uint4* tbase = &kbuf[cur][l5 * 32 + ln];   // one addr, imm offsets
      #pragma unroll
      for (int nb = 0; nb < 2; ++nb) {
        const int kbase = ktb + nb * 32;
        if (kbase > qrow0 + 31) continue;
        f32x16 sacc = {0.f,0.f,0.f,0.f,0.f,0.f,0.f,0.f,
                       0.f,0.f,0.f,0.f,0.f,0.f,0.f,0.f};
        __builtin_amdgcn_s_setprio(1);
        #pragma unroll
        for (int kb8 = 0; kb8 < 8; ++kb8) {
          const bf16x8 bf = *reinterpret_cast<const bf16x8*>(&tbase[(nb * 8 + kb8) * 64]);
          sacc = __builtin_amdgcn_mfma_f32_32x32x16_bf16(qfrag[kb8], bf, sacc, 0, 0, 0);
        }
        __builtin_amdgcn_s_setprio(0);
        const float vsv = vsbuf[cur][nb * 32 + ln];
        if (kbase + 31 <= qrow0) {
          // interior tile: no mask -> 3 ops/element
          #pragma unroll
          for (int r = 0; r < 16; ++r) {
            const float e = EXP2F(sacc[r]);
            den[r] += e;
            num[r] = fmaf(e, vsv, num[r]);
          }
        } else {
          // diagonal tile: per-element causal mask
          const int kgc = kbase + ln;
          #pragma unroll
          for (int r = 0; r < 16; ++r) {
            const int qgr = qrow0 + (r & 3) + 8 * (r >> 2) + 4 * l5;
            const float e = (kgc <= qgr) ? EXP2F(sacc[r]) : 0.f;
            den[r] += e;
            num[r] = fmaf(e, vsv, num[r]);
          }
        }
      }
    }
    cur ^= 1;
  }

  // Reduce across the 32 lanes sharing l5 (columns) -> full row sums.
  #pragma unroll
  for (int m = 1; m < 32; m <<= 1) {
    #pragma unroll
    for (int r = 0; r < 16; ++r) {
      num[r] += __shfl_xor(num[r], m);
      den[r] += __shfl_xor(den[r], m);
    }
  }
  float contrib = 0.f;
  #pragma unroll
  for (int r = 0; r < 16; ++r) contrib += num[r] / den[r];
  contrib += __shfl_xor(contrib, 32);   // other l5 half covers rows +4
  if (l == 0) atomicAdd(out, contrib);
}

extern "C" void kernel_launch(void* const* d_in, const int* in_sizes, int n_in,
                              void* d_out, int out_size, void* d_ws, size_t ws_size,
                              hipStream_t stream) {
  const float* q = (const float*)d_in[0];
  const float* k = (const float*)d_in[1];
  const float* v = (const float*)d_in[2];
  float* out = (float*)d_out;

  unsigned short* qb = (unsigned short*)d_ws;                 // 32 MiB
  unsigned short* kb = qb + (size_t)R_ * D_;                  // 32 MiB
  float* vsum = (float*)(kb + (size_t)R_ * D_);               // 512 KiB

  hipLaunchKernelGGL(prep, dim3(QKBLKS + R_ / 4), dim3(256), 0, stream,
                     q, k, v, qb, kb, vsum, out);
  hipLaunchKernelGGL(attn_sum, dim3((S_ / 128) * B_ * H_), dim3(256), 0, stream,
                     qb, kb, vsum, out);
}